// Round 3
// baseline (152.033 us; speedup 1.0000x reference)
//
#include <hip/hip_runtime.h>
#include <hip/hip_cooperative_groups.h>

namespace cg = cooperative_groups;

// SoftSymmetricAlignment: B=4, N=M=512, D=128, fp32.
// z[b,n,m] = sum_d |x[b,n,d]-y[b,m,d]|; alpha=softmax_n(-z), beta=softmax_m(-z)
// over the valid region only (masked -1e9 entries underflow to exactly 0);
// a = alpha+beta-alpha*beta; out[b] = -sum(a*z)/sum(a).
//
// R3: single cooperative kernel. z stays in registers (16 vals/thread);
// per-tile softmax partials -> global; grid.sync(); each block redundantly
// merges the stats for its own rows/cols; final accumulation from register z;
// grid.sync(); block 0 writes out. Removes 4 dispatches + 8 MB z traffic.

constexpr int B = 4, N = 512, M = 512, D = 128;
constexpr int TN = 64, TM = 64;
constexpr int LSTR = D + 4;           // +4 floats pad: rows shift 4 banks -> <=2-way conflicts
#define SENT -3.0e38f                  // "minus infinity" that is exp-safe (no inf-inf NaN)

// lengths: jnp.int64 in the reference, but JAX w/o x64 gives int32. Lengths are
// >=64, so odd int32 slots are 0 iff the buffer is int64 little-endian.
__device__ __forceinline__ int load_len(const int* p, int b) {
  bool is64 = (p[1] == 0) && (p[3] == 0);
  return is64 ? p[2 * b] : p[b];
}

__global__ __launch_bounds__(256) void k_fused(const float* __restrict__ x,
                                               const float* __restrict__ y,
                                               const int* __restrict__ xlen,
                                               const int* __restrict__ ylen,
                                               float2* __restrict__ rp,
                                               float2* __restrict__ cp,
                                               float* __restrict__ acc,
                                               float* __restrict__ out) {
  __shared__ float xs[TN * LSTR];
  __shared__ float ys[TM * LSTR];
  __shared__ float2 colp[4][TM];
  __shared__ float rm_s[TN], ri_s[TN], cm_s[TM], ci_s[TM];

  const int b  = blockIdx.z;
  const int n0 = blockIdx.y * TN;
  const int m0 = blockIdx.x * TM;
  const int tid = threadIdx.x;
  const int xl = load_len(xlen, b);
  const int yl = load_len(ylen, b);
  const bool block0 = (blockIdx.x == 0) && (blockIdx.y == 0) && (blockIdx.z == 0);

  if (block0 && tid < 2 * B) acc[tid] = 0.f;   // visible after grid.sync()

  // ---------------- phase 1: z tile in registers + softmax partials ----------
  const float4* xg = (const float4*)(x + (size_t)(b * N + n0) * D);
  const float4* yg = (const float4*)(y + (size_t)(b * M + m0) * D);
#pragma unroll
  for (int k = 0; k < 8; ++k) {
    int idx = tid + k * 256;     // float4 index within 64x128 tile (2048 total)
    int r = idx >> 5;            // 32 float4 per row
    int c = (idx & 31) << 2;
    *(float4*)&xs[r * LSTR + c] = xg[idx];
    *(float4*)&ys[r * LSTR + c] = yg[idx];
  }
  __syncthreads();

  const int tx = tid & 15;       // m group (lane bits 0..3)
  const int ty = tid >> 4;       // n group (lane bits 4..5 within wave + wave id)
  const int wv = tid >> 6;
  float zr[4][4];
#pragma unroll
  for (int i = 0; i < 4; ++i)
#pragma unroll
    for (int j = 0; j < 4; ++j) zr[i][j] = 0.f;

  // Micro-tile is STRIDED (n = n0+ty+16i, m = m0+tx+16j): within a wave the 16
  // tx lanes hit rows tx+16j -> banks 4*tx%32 = 2-way (free); x reads broadcast.
#pragma unroll 4
  for (int dd = 0; dd < D; dd += 4) {
    float4 xa[4], yb[4];
#pragma unroll
    for (int i = 0; i < 4; ++i) xa[i] = *(const float4*)&xs[(ty + 16 * i) * LSTR + dd];
#pragma unroll
    for (int j = 0; j < 4; ++j) yb[j] = *(const float4*)&ys[(tx + 16 * j) * LSTR + dd];
#pragma unroll
    for (int i = 0; i < 4; ++i)
#pragma unroll
      for (int j = 0; j < 4; ++j) {
        zr[i][j] += fabsf(xa[i].x - yb[j].x);
        zr[i][j] += fabsf(xa[i].y - yb[j].y);
        zr[i][j] += fabsf(xa[i].z - yb[j].z);
        zr[i][j] += fabsf(xa[i].w - yb[j].w);
      }
  }

  // row partials: reduce over the 16 tx lanes (lane bits 0..3)
#pragma unroll
  for (int i = 0; i < 4; ++i) {
    float lm = SENT;
#pragma unroll
    for (int j = 0; j < 4; ++j)
      if (m0 + tx + 16 * j < yl) lm = fmaxf(lm, -zr[i][j]);
#pragma unroll
    for (int off = 1; off <= 8; off <<= 1) lm = fmaxf(lm, __shfl_xor(lm, off, 64));
    float ls = 0.f;
#pragma unroll
    for (int j = 0; j < 4; ++j)
      if (m0 + tx + 16 * j < yl) ls += __expf(-zr[i][j] - lm);
#pragma unroll
    for (int off = 1; off <= 8; off <<= 1) ls += __shfl_xor(ls, off, 64);
    if (tx == 0)
      rp[((b * 8 + (m0 >> 6)) * N) + n0 + ty + 16 * i] = make_float2(lm, ls);
  }

  // col partials: reduce ty within wave (lane bits 4..5), then 4 waves via LDS
#pragma unroll
  for (int j = 0; j < 4; ++j) {
    float cm = SENT;
#pragma unroll
    for (int i = 0; i < 4; ++i)
      if (n0 + ty + 16 * i < xl) cm = fmaxf(cm, -zr[i][j]);
    cm = fmaxf(cm, __shfl_xor(cm, 16, 64));
    cm = fmaxf(cm, __shfl_xor(cm, 32, 64));
    float cs = 0.f;
#pragma unroll
    for (int i = 0; i < 4; ++i)
      if (n0 + ty + 16 * i < xl) cs += __expf(-zr[i][j] - cm);
    cs += __shfl_xor(cs, 16, 64);
    cs += __shfl_xor(cs, 32, 64);
    if ((ty & 3) == 0) colp[wv][tx + 16 * j] = make_float2(cm, cs);
  }
  __syncthreads();
  if (tid < TM) {
    float2 p0 = colp[0][tid], p1 = colp[1][tid], p2 = colp[2][tid], p3 = colp[3][tid];
    float gm = fmaxf(fmaxf(p0.x, p1.x), fmaxf(p2.x, p3.x));
    float gs = p0.y * __expf(p0.x - gm) + p1.y * __expf(p1.x - gm) +
               p2.y * __expf(p2.x - gm) + p3.y * __expf(p3.x - gm);
    cp[((b * 8 + (n0 >> 6)) * M) + m0 + tid] = make_float2(gm, gs);
  }

  cg::this_grid().sync();

  // ---------------- phase 2: merge stats for THIS block's rows/cols ----------
  // tid<64: row n0+tid; tid in [64,128): col m0+(tid-64). 8 partials each,
  // online-softmax rescale; masked partials (sum 0) contribute exactly 0.
  if (tid < 128) {
    bool isrow = tid < 64;
    int p = isrow ? (n0 + tid) : (m0 + tid - 64);
    const float2* src = isrow ? rp : cp;
    float2 v[8];
    float gm = SENT;
#pragma unroll
    for (int t = 0; t < 8; ++t) {
      v[t] = src[(b * 8 + t) * 512 + p];
      gm = fmaxf(gm, v[t].x);
    }
    float gs = 0.f;
#pragma unroll
    for (int t = 0; t < 8; ++t) gs += v[t].y * __expf(v[t].x - gm);
    float inv = 1.0f / gs;            // inf only for fully-masked rows/cols (unused)
    if (isrow) { rm_s[tid] = gm; ri_s[tid] = inv; }
    else       { cm_s[tid - 64] = gm; ci_s[tid - 64] = inv; }
  }
  __syncthreads();

  // ---------------- phase 3: a = alpha+beta-alpha*beta from register z -------
  float num = 0.f, den = 0.f;
#pragma unroll
  for (int i = 0; i < 4; ++i) {
    int nl = ty + 16 * i;
    if (n0 + nl >= xl) continue;
    float rm = rm_s[nl], ri = ri_s[nl];
#pragma unroll
    for (int j = 0; j < 4; ++j) {
      int ml = tx + 16 * j;
      if (m0 + ml >= yl) continue;
      float zv = zr[i][j];
      float w = -zv;
      float alpha = __expf(w - cm_s[ml]) * ci_s[ml];
      float beta  = __expf(w - rm) * ri;
      float a = alpha + beta - alpha * beta;
      num += a * zv;
      den += a;
    }
  }
#pragma unroll
  for (int off = 32; off > 0; off >>= 1) {
    num += __shfl_xor(num, off, 64);
    den += __shfl_xor(den, off, 64);
  }
  if ((tid & 63) == 0) {
    atomicAdd(&acc[b], num);
    atomicAdd(&acc[B + b], den);
  }

  cg::this_grid().sync();

  if (block0 && tid < B) out[tid] = -acc[tid] / acc[B + tid];
}

extern "C" void kernel_launch(void* const* d_in, const int* in_sizes, int n_in,
                              void* d_out, int out_size, void* d_ws, size_t ws_size,
                              hipStream_t stream) {
  const float* x    = (const float*)d_in[0];
  const float* y    = (const float*)d_in[1];
  const int*   xlen = (const int*)d_in[2];
  const int*   ylen = (const int*)d_in[3];
  float* out = (float*)d_out;

  float* ws = (float*)d_ws;
  float2* rp  = (float2*)ws;              size_t off = (size_t)B * 8 * N * 2;  // 128 KB
  float2* cp  = (float2*)(ws + off);      off += (size_t)B * 8 * M * 2;        // 128 KB
  float*  acc = ws + off;                 off += 2 * B;

  void* args[] = {(void*)&x, (void*)&y, (void*)&xlen, (void*)&ylen,
                  (void*)&rp, (void*)&cp, (void*)&acc, (void*)&out};
  hipLaunchCooperativeKernel((void*)k_fused, dim3(M / TM, N / TN, B), dim3(256),
                             args, 0, stream);
}

// Round 4
// 114.545 us; speedup vs baseline: 1.3273x; 1.3273x over previous
//
#include <hip/hip_runtime.h>

// SoftSymmetricAlignment: B=4, N=M=512, D=128, fp32.
// z[b,n,m] = sum_d |x[b,n,d]-y[b,m,d]|; alpha=softmax_n(-z), beta=softmax_m(-z)
// over the valid region only (masked -1e9 entries underflow to exactly 0);
// a = alpha+beta-alpha*beta; out[b] = -sum(a*z)/sum(a).
//
// R4: back to stream-ordered kernels (R3 showed cg grid.sync ~30us each on
// gfx950 — 77us kernel at 10% VALUBusy). Two dispatches total:
//   k_zdiff : z tile in registers -> z + per-tile softmax partials (+ zeroes acc)
//   k_final2: redundant per-block stat merge (LDS) + a-accumulation +
//             last-block-finishes output write. Replaces merge/final/out/memset.

constexpr int B = 4, N = 512, M = 512, D = 128;
constexpr int TN = 64, TM = 64;
constexpr int LSTR = D + 4;           // +4 floats pad: rows shift 4 banks -> <=2-way conflicts
#define SENT -3.0e38f                  // "minus infinity" that is exp-safe (no inf-inf NaN)

// lengths: jnp.int64 in the reference, but JAX w/o x64 gives int32. Lengths are
// >=64, so odd int32 slots are 0 iff the buffer is int64 little-endian.
__device__ __forceinline__ int load_len(const int* p, int b) {
  bool is64 = (p[1] == 0) && (p[3] == 0);
  return is64 ? p[2 * b] : p[b];
}

__global__ __launch_bounds__(256) void k_zdiff(const float* __restrict__ x,
                                               const float* __restrict__ y,
                                               const int* __restrict__ xlen,
                                               const int* __restrict__ ylen,
                                               float* __restrict__ z,
                                               float2* __restrict__ rp,
                                               float2* __restrict__ cp,
                                               float* __restrict__ acc,
                                               unsigned* __restrict__ counter) {
  __shared__ float xs[TN * LSTR];
  __shared__ float ys[TM * LSTR];
  __shared__ float2 colp[4][TM];
  const int b  = blockIdx.z;
  const int n0 = blockIdx.y * TN;
  const int m0 = blockIdx.x * TM;
  const int tid = threadIdx.x;
  const int xl = load_len(xlen, b);
  const int yl = load_len(ylen, b);

  // zero the accumulators for k_final2 (ws is re-poisoned before every launch;
  // kernel-boundary release makes this visible to the next dispatch)
  if (blockIdx.x == 0 && blockIdx.y == 0 && blockIdx.z == 0) {
    if (tid < 2 * B) acc[tid] = 0.f;
    if (tid == 2 * B) *counter = 0u;
  }

  // Tiles are contiguous 32KB chunks in global (full D range, consecutive rows).
  const float4* xg = (const float4*)(x + (size_t)(b * N + n0) * D);
  const float4* yg = (const float4*)(y + (size_t)(b * M + m0) * D);
#pragma unroll
  for (int k = 0; k < 8; ++k) {
    int idx = tid + k * 256;     // float4 index within tile (2048 total)
    int r = idx >> 5;            // 32 float4 per row
    int c = (idx & 31) << 2;
    *(float4*)&xs[r * LSTR + c] = xg[idx];
    *(float4*)&ys[r * LSTR + c] = yg[idx];
  }
  __syncthreads();

  const int tx = tid & 15;       // m group (lane bits 0..3)
  const int ty = tid >> 4;       // n group (lane bits 4..5 within wave + wave id)
  const int wv = tid >> 6;
  float zr[4][4];
#pragma unroll
  for (int i = 0; i < 4; ++i)
#pragma unroll
    for (int j = 0; j < 4; ++j) zr[i][j] = 0.f;

  // Micro-tile is STRIDED (n = n0+ty+16i, m = m0+tx+16j): within a wave the 16
  // tx lanes hit rows tx+16j -> banks 4*tx%32 = 2-way (free); x reads broadcast.
#pragma unroll 4
  for (int dd = 0; dd < D; dd += 4) {
    float4 xa[4], yb[4];
#pragma unroll
    for (int i = 0; i < 4; ++i) xa[i] = *(const float4*)&xs[(ty + 16 * i) * LSTR + dd];
#pragma unroll
    for (int j = 0; j < 4; ++j) yb[j] = *(const float4*)&ys[(tx + 16 * j) * LSTR + dd];
#pragma unroll
    for (int i = 0; i < 4; ++i)
#pragma unroll
      for (int j = 0; j < 4; ++j) {
        zr[i][j] += fabsf(xa[i].x - yb[j].x);
        zr[i][j] += fabsf(xa[i].y - yb[j].y);
        zr[i][j] += fabsf(xa[i].z - yb[j].z);
        zr[i][j] += fabsf(xa[i].w - yb[j].w);
      }
  }

  // z store
  float* zb = z + (size_t)b * N * M;
#pragma unroll
  for (int i = 0; i < 4; ++i) {
    int n = n0 + ty + 16 * i;
#pragma unroll
    for (int j = 0; j < 4; ++j) zb[n * M + m0 + tx + 16 * j] = zr[i][j];
  }

  // row partials: reduce over the 16 tx lanes (lane bits 0..3)
#pragma unroll
  for (int i = 0; i < 4; ++i) {
    float lm = SENT;
#pragma unroll
    for (int j = 0; j < 4; ++j)
      if (m0 + tx + 16 * j < yl) lm = fmaxf(lm, -zr[i][j]);
#pragma unroll
    for (int off = 1; off <= 8; off <<= 1) lm = fmaxf(lm, __shfl_xor(lm, off, 64));
    float ls = 0.f;
#pragma unroll
    for (int j = 0; j < 4; ++j)
      if (m0 + tx + 16 * j < yl) ls += __expf(-zr[i][j] - lm);
#pragma unroll
    for (int off = 1; off <= 8; off <<= 1) ls += __shfl_xor(ls, off, 64);
    if (tx == 0)
      rp[((b * 8 + (m0 >> 6)) * N) + n0 + ty + 16 * i] = make_float2(lm, ls);
  }

  // col partials: reduce ty within wave (lane bits 4..5), then 4 waves via LDS
#pragma unroll
  for (int j = 0; j < 4; ++j) {
    float cm = SENT;
#pragma unroll
    for (int i = 0; i < 4; ++i)
      if (n0 + ty + 16 * i < xl) cm = fmaxf(cm, -zr[i][j]);
    cm = fmaxf(cm, __shfl_xor(cm, 16, 64));
    cm = fmaxf(cm, __shfl_xor(cm, 32, 64));
    float cs = 0.f;
#pragma unroll
    for (int i = 0; i < 4; ++i)
      if (n0 + ty + 16 * i < xl) cs += __expf(-zr[i][j] - cm);
    cs += __shfl_xor(cs, 16, 64);
    cs += __shfl_xor(cs, 32, 64);
    if ((ty & 3) == 0) colp[wv][tx + 16 * j] = make_float2(cm, cs);
  }
  __syncthreads();
  if (tid < TM) {
    float2 p0 = colp[0][tid], p1 = colp[1][tid], p2 = colp[2][tid], p3 = colp[3][tid];
    float gm = fmaxf(fmaxf(p0.x, p1.x), fmaxf(p2.x, p3.x));
    float gs = p0.y * __expf(p0.x - gm) + p1.y * __expf(p1.x - gm) +
               p2.y * __expf(p2.x - gm) + p3.y * __expf(p3.x - gm);
    cp[((b * 8 + (n0 >> 6)) * M) + m0 + tid] = make_float2(gm, gs);
  }
}

// One block per (8-row group, batch). Merges stats redundantly into LDS,
// accumulates num/den, last block writes out.
__global__ __launch_bounds__(256) void k_final2(const float* __restrict__ z,
                                                const int* __restrict__ xlen,
                                                const int* __restrict__ ylen,
                                                const float2* __restrict__ rp,
                                                const float2* __restrict__ cp,
                                                float* __restrict__ acc,
                                                unsigned* __restrict__ counter,
                                                float* __restrict__ out) {
  __shared__ float cm_s[M], ci_s[M];
  __shared__ float rm_s[8], ri_s[8];
  const int b  = blockIdx.y;
  const int n0 = blockIdx.x * 8;
  const int tid = threadIdx.x;
  const int xl = load_len(xlen, b);
  const int yl = load_len(ylen, b);

  // merge col stats (all 512 cols of batch b; 2 cols/thread, 8 partials each)
  for (int m = tid; m < M; m += 256) {
    float2 v[8];
    float gm = SENT;
#pragma unroll
    for (int t = 0; t < 8; ++t) {
      v[t] = cp[(b * 8 + t) * M + m];
      gm = fmaxf(gm, v[t].x);
    }
    float gs = 0.f;
#pragma unroll
    for (int t = 0; t < 8; ++t) gs += v[t].y * __expf(v[t].x - gm);
    cm_s[m] = gm;
    ci_s[m] = 1.0f / gs;          // inf only for m>=yl (never read in phase 3)
  }
  // merge row stats for this block's 8 rows
  if (tid < 8) {
    float2 v[8];
    float gm = SENT;
#pragma unroll
    for (int t = 0; t < 8; ++t) {
      v[t] = rp[(b * 8 + t) * N + n0 + tid];
      gm = fmaxf(gm, v[t].x);
    }
    float gs = 0.f;
#pragma unroll
    for (int t = 0; t < 8; ++t) gs += v[t].y * __expf(v[t].x - gm);
    rm_s[tid] = gm;
    ri_s[tid] = 1.0f / gs;
  }
  __syncthreads();

  float num = 0.f, den = 0.f;
  for (int k = 0; k < 8; ++k) {
    int n = n0 + k;
    if (n >= xl) break;                    // xl uniform across block
    float rm = rm_s[k], ri = ri_s[k];
    const float* zrow = z + ((size_t)b * N + n) * M;
    for (int m = tid; m < yl; m += 256) {
      float zv = zrow[m];
      float w = -zv;
      float alpha = __expf(w - cm_s[m]) * ci_s[m];
      float beta  = __expf(w - rm) * ri;
      float a = alpha + beta - alpha * beta;
      num += a * zv;
      den += a;
    }
  }
#pragma unroll
  for (int off = 32; off > 0; off >>= 1) {
    num += __shfl_xor(num, off, 64);
    den += __shfl_xor(den, off, 64);
  }
  if ((tid & 63) == 0) {
    atomicAdd(&acc[b], num);
    atomicAdd(&acc[B + b], den);
  }
  __threadfence();                          // order this block's acc atomics
  __syncthreads();                          // before the counter increment
  if (tid == 0) {
    unsigned old = atomicAdd(counter, 1u);
    if (old == gridDim.x * gridDim.y - 1) { // last block: everyone's acc visible
      for (int i = 0; i < B; ++i) {
        float nsum = atomicAdd(&acc[i], 0.f);      // coherent-point reads
        float dsum = atomicAdd(&acc[B + i], 0.f);
        out[i] = -nsum / dsum;
      }
    }
  }
}

extern "C" void kernel_launch(void* const* d_in, const int* in_sizes, int n_in,
                              void* d_out, int out_size, void* d_ws, size_t ws_size,
                              hipStream_t stream) {
  const float* x    = (const float*)d_in[0];
  const float* y    = (const float*)d_in[1];
  const int*   xlen = (const int*)d_in[2];
  const int*   ylen = (const int*)d_in[3];
  float* out = (float*)d_out;

  float* ws = (float*)d_ws;
  float*    z       = ws;                    size_t off = (size_t)B * N * M;   // 4 MB
  float2*   rp      = (float2*)(ws + off);   off += (size_t)B * 8 * N * 2;     // 128 KB
  float2*   cp      = (float2*)(ws + off);   off += (size_t)B * 8 * M * 2;     // 128 KB
  float*    acc     = ws + off;              off += 2 * B;
  unsigned* counter = (unsigned*)(ws + off); off += 1;

  k_zdiff<<<dim3(M / TM, N / TN, B), 256, 0, stream>>>(x, y, xlen, ylen, z, rp, cp,
                                                       acc, counter);
  k_final2<<<dim3(N / 8, B), 256, 0, stream>>>(z, xlen, ylen, rp, cp, acc, counter, out);
}

// Round 5
// 96.318 us; speedup vs baseline: 1.5784x; 1.1892x over previous
//
#include <hip/hip_runtime.h>

// SoftSymmetricAlignment: B=4, N=M=512, D=128, fp32.
// z[b,n,m] = sum_d |x[b,n,d]-y[b,m,d]|; alpha=softmax_n(-z), beta=softmax_m(-z)
// over the valid region only (masked -1e9 entries underflow to exactly 0);
// a = alpha+beta-alpha*beta; out[b] = -sum(a*z)/sum(a).
//
// R5: flash-style recompute. R4 showed memory-latency kernels get stretched to
// ~43us (overlap with the harness's 268MB 0xAA ws-poison fill saturating HBM;
// plus __threadfence = buffer_wbl2). So: NO z tensor at all. k1 computes z in
// registers -> per-tile softmax partials only (256 KB). k2 recomputes z in
// registers, merges stats per block in LDS, accumulates num/den -> 2 atomics
// per block. k3 (1 block) writes out. All heavy kernels are compute-bound.

constexpr int B = 4, N = 512, M = 512, D = 128;
constexpr int TN = 64, TM = 64;
constexpr int LSTR = D + 4;           // +4 floats pad: rows shift 4 banks -> <=2-way conflicts
#define SENT -3.0e38f                  // "minus infinity" that is exp-safe (no inf-inf NaN)

// lengths: jnp.int64 in the reference, but JAX w/o x64 gives int32. Lengths are
// >=64, so odd int32 slots are 0 iff the buffer is int64 little-endian.
__device__ __forceinline__ int load_len(const int* p, int b) {
  bool is64 = (p[1] == 0) && (p[3] == 0);
  return is64 ? p[2 * b] : p[b];
}

// Shared tile-compute: stages x/y 64x128 tiles into LDS, returns zr[4][4] for
// n = n0+ty+16i, m = m0+tx+16j (strided micro-tile; <=2-way LDS conflicts).
__device__ __forceinline__ void compute_tile(const float* __restrict__ x,
                                             const float* __restrict__ y,
                                             int b, int n0, int m0, int tid,
                                             float* xs, float* ys,
                                             float zr[4][4]) {
  const float4* xg = (const float4*)(x + (size_t)(b * N + n0) * D);
  const float4* yg = (const float4*)(y + (size_t)(b * M + m0) * D);
#pragma unroll
  for (int k = 0; k < 8; ++k) {
    int idx = tid + k * 256;     // float4 index within 64x128 tile (2048 total)
    int r = idx >> 5;            // 32 float4 per row
    int c = (idx & 31) << 2;
    *(float4*)&xs[r * LSTR + c] = xg[idx];
    *(float4*)&ys[r * LSTR + c] = yg[idx];
  }
  __syncthreads();

  const int tx = tid & 15;
  const int ty = tid >> 4;
#pragma unroll
  for (int i = 0; i < 4; ++i)
#pragma unroll
    for (int j = 0; j < 4; ++j) zr[i][j] = 0.f;

#pragma unroll 4
  for (int dd = 0; dd < D; dd += 4) {
    float4 xa[4], yb[4];
#pragma unroll
    for (int i = 0; i < 4; ++i) xa[i] = *(const float4*)&xs[(ty + 16 * i) * LSTR + dd];
#pragma unroll
    for (int j = 0; j < 4; ++j) yb[j] = *(const float4*)&ys[(tx + 16 * j) * LSTR + dd];
#pragma unroll
    for (int i = 0; i < 4; ++i)
#pragma unroll
      for (int j = 0; j < 4; ++j) {
        zr[i][j] += fabsf(xa[i].x - yb[j].x);
        zr[i][j] += fabsf(xa[i].y - yb[j].y);
        zr[i][j] += fabsf(xa[i].z - yb[j].z);
        zr[i][j] += fabsf(xa[i].w - yb[j].w);
      }
  }
}

// k1: per-tile softmax partials only.
//   rp[b][mt][n] = (max, sumexp) over this m-tile's valid m, for row n
//   cp[b][nt][m] = (max, sumexp) over this n-tile's valid n, for col m
__global__ __launch_bounds__(256) void k1_stats(const float* __restrict__ x,
                                                const float* __restrict__ y,
                                                const int* __restrict__ xlen,
                                                const int* __restrict__ ylen,
                                                float2* __restrict__ rp,
                                                float2* __restrict__ cp,
                                                float* __restrict__ acc) {
  __shared__ float xs[TN * LSTR];
  __shared__ float ys[TM * LSTR];
  __shared__ float2 colp[4][TM];
  const int b  = blockIdx.z;
  const int n0 = blockIdx.y * TN;
  const int m0 = blockIdx.x * TM;
  const int tid = threadIdx.x;
  const int xl = load_len(xlen, b);
  const int yl = load_len(ylen, b);

  if (blockIdx.x == 0 && blockIdx.y == 0 && blockIdx.z == 0 && tid < 2 * B)
    acc[tid] = 0.f;   // visible to k2's atomics after kernel boundary

  float zr[4][4];
  compute_tile(x, y, b, n0, m0, tid, xs, ys, zr);

  const int tx = tid & 15;
  const int ty = tid >> 4;
  const int wv = tid >> 6;

  // row partials: reduce over the 16 tx lanes (lane bits 0..3)
#pragma unroll
  for (int i = 0; i < 4; ++i) {
    float lm = SENT;
#pragma unroll
    for (int j = 0; j < 4; ++j)
      if (m0 + tx + 16 * j < yl) lm = fmaxf(lm, -zr[i][j]);
#pragma unroll
    for (int off = 1; off <= 8; off <<= 1) lm = fmaxf(lm, __shfl_xor(lm, off, 64));
    float ls = 0.f;
#pragma unroll
    for (int j = 0; j < 4; ++j)
      if (m0 + tx + 16 * j < yl) ls += __expf(-zr[i][j] - lm);
#pragma unroll
    for (int off = 1; off <= 8; off <<= 1) ls += __shfl_xor(ls, off, 64);
    if (tx == 0)
      rp[((b * 8 + (m0 >> 6)) * N) + n0 + ty + 16 * i] = make_float2(lm, ls);
  }

  // col partials: reduce ty within wave (lane bits 4..5), then 4 waves via LDS
#pragma unroll
  for (int j = 0; j < 4; ++j) {
    float cm = SENT;
#pragma unroll
    for (int i = 0; i < 4; ++i)
      if (n0 + ty + 16 * i < xl) cm = fmaxf(cm, -zr[i][j]);
    cm = fmaxf(cm, __shfl_xor(cm, 16, 64));
    cm = fmaxf(cm, __shfl_xor(cm, 32, 64));
    float cs = 0.f;
#pragma unroll
    for (int i = 0; i < 4; ++i)
      if (n0 + ty + 16 * i < xl) cs += __expf(-zr[i][j] - cm);
    cs += __shfl_xor(cs, 16, 64);
    cs += __shfl_xor(cs, 32, 64);
    if ((ty & 3) == 0) colp[wv][tx + 16 * j] = make_float2(cm, cs);
  }
  __syncthreads();
  if (tid < TM) {
    float2 p0 = colp[0][tid], p1 = colp[1][tid], p2 = colp[2][tid], p3 = colp[3][tid];
    float gm = fmaxf(fmaxf(p0.x, p1.x), fmaxf(p2.x, p3.x));
    float gs = p0.y * __expf(p0.x - gm) + p1.y * __expf(p1.x - gm) +
               p2.y * __expf(p2.x - gm) + p3.y * __expf(p3.x - gm);
    cp[((b * 8 + (n0 >> 6)) * M) + m0 + tid] = make_float2(gm, gs);
  }
}

// k2: recompute zr, merge this block's row/col stats, accumulate num/den.
__global__ __launch_bounds__(256) void k2_final(const float* __restrict__ x,
                                                const float* __restrict__ y,
                                                const int* __restrict__ xlen,
                                                const int* __restrict__ ylen,
                                                const float2* __restrict__ rp,
                                                const float2* __restrict__ cp,
                                                float* __restrict__ acc) {
  __shared__ float xs[TN * LSTR];
  __shared__ float ys[TM * LSTR];
  __shared__ float rm_s[TN], ri_s[TN], cm_s[TM], ci_s[TM];
  __shared__ float red[4][2];
  const int b  = blockIdx.z;
  const int n0 = blockIdx.y * TN;
  const int m0 = blockIdx.x * TM;
  const int tid = threadIdx.x;
  const int xl = load_len(xlen, b);
  const int yl = load_len(ylen, b);

  // merge the 8 per-tile partials for this block's rows (tid<64) / cols
  // (64<=tid<128); online-softmax rescale, masked partials contribute 0.
  if (tid < 128) {
    bool isrow = tid < 64;
    int p = isrow ? (n0 + tid) : (m0 + tid - 64);
    const float2* src = isrow ? rp : cp;
    float2 v[8];
    float gm = SENT;
#pragma unroll
    for (int t = 0; t < 8; ++t) {
      v[t] = src[(b * 8 + t) * 512 + p];
      gm = fmaxf(gm, v[t].x);
    }
    float gs = 0.f;
#pragma unroll
    for (int t = 0; t < 8; ++t) gs += v[t].y * __expf(v[t].x - gm);
    float inv = 1.0f / gs;            // inf only for fully-masked rows/cols (unused)
    if (isrow) { rm_s[tid] = gm; ri_s[tid] = inv; }
    else       { cm_s[tid - 64] = gm; ci_s[tid - 64] = inv; }
  }
  // compute_tile's __syncthreads() covers the stat merge too

  float zr[4][4];
  compute_tile(x, y, b, n0, m0, tid, xs, ys, zr);

  const int tx = tid & 15;
  const int ty = tid >> 4;
  float num = 0.f, den = 0.f;
#pragma unroll
  for (int i = 0; i < 4; ++i) {
    int nl = ty + 16 * i;
    if (n0 + nl >= xl) continue;
    float rm = rm_s[nl], ri = ri_s[nl];
#pragma unroll
    for (int j = 0; j < 4; ++j) {
      int ml = tx + 16 * j;
      if (m0 + ml >= yl) continue;
      float zv = zr[i][j];
      float w = -zv;
      float alpha = __expf(w - cm_s[ml]) * ci_s[ml];
      float beta  = __expf(w - rm) * ri;
      float a = alpha + beta - alpha * beta;
      num += a * zv;
      den += a;
    }
  }
#pragma unroll
  for (int off = 32; off > 0; off >>= 1) {
    num += __shfl_xor(num, off, 64);
    den += __shfl_xor(den, off, 64);
  }
  __syncthreads();                      // LDS reuse barrier (xs/ys done)
  if ((tid & 63) == 0) { red[tid >> 6][0] = num; red[tid >> 6][1] = den; }
  __syncthreads();
  if (tid == 0) {
    float n4 = red[0][0] + red[1][0] + red[2][0] + red[3][0];
    float d4 = red[0][1] + red[1][1] + red[2][1] + red[3][1];
    atomicAdd(&acc[b], n4);
    atomicAdd(&acc[B + b], d4);
  }
}

__global__ void k3_out(const float* __restrict__ acc, float* __restrict__ out) {
  int b = threadIdx.x;
  if (b < B) out[b] = -acc[b] / acc[B + b];
}

extern "C" void kernel_launch(void* const* d_in, const int* in_sizes, int n_in,
                              void* d_out, int out_size, void* d_ws, size_t ws_size,
                              hipStream_t stream) {
  const float* x    = (const float*)d_in[0];
  const float* y    = (const float*)d_in[1];
  const int*   xlen = (const int*)d_in[2];
  const int*   ylen = (const int*)d_in[3];
  float* out = (float*)d_out;

  float* ws = (float*)d_ws;
  float2* rp  = (float2*)ws;              size_t off = (size_t)B * 8 * N * 2;  // 128 KB
  float2* cp  = (float2*)(ws + off);      off += (size_t)B * 8 * M * 2;        // 128 KB
  float*  acc = ws + off;                 off += 2 * B;

  k1_stats<<<dim3(M / TM, N / TN, B), 256, 0, stream>>>(x, y, xlen, ylen, rp, cp, acc);
  k2_final<<<dim3(M / TM, N / TN, B), 256, 0, stream>>>(x, y, xlen, ylen, rp, cp, acc);
  k3_out<<<1, 64, 0, stream>>>(acc, out);
}